// Round 1
// baseline (4958.495 us; speedup 1.0000x reference)
//
#include <hip/hip_runtime.h>
#include <math.h>

#define LSEQ 4096
#define DIMC 256
#define DI   512

__device__ __forceinline__ float sp_f(float v){ return fmaxf(v,0.f) + log1pf(__expf(-fabsf(v))); }
__device__ __forceinline__ float silu_f(float v){ return v/(1.f+__expf(-v)); }

// ---------------- LayerNorm over channel dim: x (B,C,L) -> h (B*L, C) ----------------
__global__ __launch_bounds__(64) void ln_kernel(const float* __restrict__ x,
                                                const float* __restrict__ w,
                                                const float* __restrict__ bias,
                                                float* __restrict__ h){
  int row = blockIdx.x;            // b*L + l
  int b = row >> 12, l = row & 4095;
  int i = threadIdx.x;             // 0..63
  const float* xb = x + (size_t)b*DIMC*LSEQ + l;
  float v[4]; float s=0.f, sq=0.f;
  #pragma unroll
  for(int j=0;j<4;j++){ float t = xb[(size_t)(j*64+i)*LSEQ]; v[j]=t; s+=t; sq+=t*t; }
  #pragma unroll
  for(int o=1;o<64;o<<=1){ s += __shfl_xor(s,o); sq += __shfl_xor(sq,o); }
  float mu = s*(1.f/256.f);
  float var = sq*(1.f/256.f) - mu*mu;
  float rs = rsqrtf(var + 1e-5f);
  float* hr = h + (size_t)row*DIMC;
  #pragma unroll
  for(int j=0;j<4;j++){ int c=j*64+i; hr[c] = (v[j]-mu)*rs*w[c] + bias[c]; }
}

// ---------------- Generic fp32 GEMM: C[M,N] = A[M,K] * W[N,K]^T (+ epilogue) --------
// EPI 0: none.  EPI 1: softplus(acc + bias[n])
template<int EPI>
__global__ __launch_bounds__(256) void gemm_kernel(const float* __restrict__ A, int lda,
                                                   const float* __restrict__ W,
                                                   const float* __restrict__ bias,
                                                   float* __restrict__ C, int ldc,
                                                   int M, int N, int K){
  __shared__ float As[16][64];
  __shared__ float Bs[16][64];
  int tx = threadIdx.x, ty = threadIdx.y;
  int tid = ty*16+tx;
  int n0 = blockIdx.x*64, m0 = blockIdx.y*64;
  float acc[4][4] = {};
  int lr = tid>>2;        // 0..63 (row within tile)
  int kq = (tid&3)*4;     // 0,4,8,12
  for(int k0=0;k0<K;k0+=16){
    float4 av = *(const float4*)(A + (size_t)(m0+lr)*lda + k0 + kq);
    As[kq+0][lr]=av.x; As[kq+1][lr]=av.y; As[kq+2][lr]=av.z; As[kq+3][lr]=av.w;
    float4 wv = make_float4(0.f,0.f,0.f,0.f);
    if(n0+lr < N) wv = *(const float4*)(W + (size_t)(n0+lr)*K + k0 + kq);
    Bs[kq+0][lr]=wv.x; Bs[kq+1][lr]=wv.y; Bs[kq+2][lr]=wv.z; Bs[kq+3][lr]=wv.w;
    __syncthreads();
    #pragma unroll
    for(int kk=0;kk<16;kk++){
      float4 a4 = *(const float4*)&As[kk][ty*4];
      float4 b4 = *(const float4*)&Bs[kk][tx*4];
      float aa[4]={a4.x,a4.y,a4.z,a4.w}, bb[4]={b4.x,b4.y,b4.z,b4.w};
      #pragma unroll
      for(int i2=0;i2<4;i2++)
        #pragma unroll
        for(int j2=0;j2<4;j2++) acc[i2][j2] += aa[i2]*bb[j2];
    }
    __syncthreads();
  }
  #pragma unroll
  for(int i2=0;i2<4;i2++){
    int m = m0 + ty*4 + i2;
    #pragma unroll
    for(int j2=0;j2<4;j2++){
      int n = n0 + tx*4 + j2;
      if(n < N){
        float vv = acc[i2][j2];
        if(EPI==1) vv = sp_f(vv + bias[n]);
        C[(size_t)m*ldc + n] = vv;
      }
    }
  }
}

// ---------------- causal depthwise conv1d (kernel 4) + bias + SiLU -------------------
// input: u-half of xz (row stride 1024), output: u (B*L,512)
__global__ __launch_bounds__(256) void conv1d_silu_kernel(const float* __restrict__ xz,
                                                          const float* __restrict__ cw,
                                                          const float* __restrict__ cb,
                                                          float* __restrict__ u){
  int g = blockIdx.x*256 + threadIdx.x;   // b*2^21 + l*512 + d
  int d = g & 511;
  int l = (g>>9) & 4095;
  int b = g >> 21;
  const float* ub = xz + (size_t)b*LSEQ*1024 + d;
  float accv = cb[d];
  #pragma unroll
  for(int k=0;k<4;k++){
    int ls = l-3+k;
    float vv = (ls>=0) ? ub[(size_t)ls*1024] : 0.f;
    accv += vv * cw[d*4+k];
  }
  u[(size_t)g] = silu_f(accv);
}

// ---------------- selective scan: lane per (b,d,s); shfl-reduce y over s -------------
__global__ __launch_bounds__(256) void scan_kernel(const float* __restrict__ dt,
                                                   const float* __restrict__ u,
                                                   const float* __restrict__ xdbl,
                                                   const float* __restrict__ A_log,
                                                   float* __restrict__ y){
  int tid = threadIdx.x;
  int s = tid & 15;
  int p = tid >> 4;                  // 0..15
  int g = blockIdx.x*16 + p;         // 0..1023 = b*512 + d
  int b = g >> 9, d = g & 511;
  float a = -__expf(A_log[d*16+s]);
  float hc = 0.f;
  const float* dtp = dt + (size_t)b*LSEQ*512 + d;
  const float* up  = u  + (size_t)b*LSEQ*512 + d;
  const float* xb  = xdbl + (size_t)b*LSEQ*48;
  float* yp = y + (size_t)b*LSEQ*512 + d;
  for(int t=0;t<LSEQ;t++){
    float dtv = dtp[(size_t)t*512];
    float uv  = up[(size_t)t*512];
    float bv  = xb[t*48 + 16 + s];
    float cv  = xb[t*48 + 32 + s];
    float dA = __expf(dtv*a);
    hc = dA*hc + dtv*bv*uv;
    float pp = hc*cv;
    pp += __shfl_xor(pp,1);
    pp += __shfl_xor(pp,2);
    pp += __shfl_xor(pp,4);
    pp += __shfl_xor(pp,8);
    if(s==0) yp[(size_t)t*512] = pp;   // same addr as dt read: read-before-write within wave, safe
  }
}

// ---------------- y = (y + u*D) * silu(z) -------------------------------------------
__global__ __launch_bounds__(256) void ymul_kernel(float* __restrict__ y,
                                                   const float* __restrict__ u,
                                                   const float* __restrict__ xz,
                                                   const float* __restrict__ Dsk){
  int g = blockIdx.x*256 + threadIdx.x;
  int d = g & 511;
  int row = g >> 9;   // b*L + l
  float z = xz[(size_t)row*1024 + 512 + d];
  y[g] = (y[g] + u[g]*Dsk[d]) * silu_f(z);
}

// ---------------- conv3d 3x3x3 (pad 1) + PReLU + add mamba output --------------------
// block: 16x16 (y,x) plane for fixed (b, z, group of 4 output channels)
__global__ __launch_bounds__(256) void conv3d_out_kernel(const float* __restrict__ x,
                                                         const float* __restrict__ w3,
                                                         const float* __restrict__ hbuf,
                                                         const float* __restrict__ prelu_a,
                                                         const float* __restrict__ scale,
                                                         float* __restrict__ out){
  __shared__ float sm[3*18*18];
  int tx = threadIdx.x & 15, ty = threadIdx.x >> 4;
  int cg = blockIdx.x;        // 0..63 -> c = cg*4 + j
  int z  = blockIdx.y;        // 0..15
  int b  = blockIdx.z;        // 0..1
  float acc0=0.f, acc1=0.f, acc2=0.f, acc3=0.f;
  for(int ci=0; ci<256; ci++){
    const float* xs = x + (size_t)(b*256+ci)*4096;
    for(int idx=threadIdx.x; idx<972; idx+=256){
      int dz = idx/324, rem = idx - dz*324;
      int yy = rem/18, xx = rem - yy*18;
      int zz = z + dz - 1, ys = yy - 1, xsrc = xx - 1;
      float vv = 0.f;
      if((unsigned)zz < 16u && (unsigned)ys < 16u && (unsigned)xsrc < 16u)
        vv = xs[(zz*16 + ys)*16 + xsrc];
      sm[idx] = vv;
    }
    __syncthreads();
    float xv[27];
    #pragma unroll
    for(int kz=0;kz<3;kz++)
      #pragma unroll
      for(int ky=0;ky<3;ky++)
        #pragma unroll
        for(int kx=0;kx<3;kx++)
          xv[(kz*3+ky)*3+kx] = sm[kz*324 + (ty+ky)*18 + (tx+kx)];
    const float* wb = w3 + ((size_t)(cg*4)*256 + ci)*27;  // block-uniform -> scalar loads
    #pragma unroll
    for(int kk=0; kk<27; kk++){
      float xvv = xv[kk];
      acc0 += xvv * wb[kk];
      acc1 += xvv * wb[1*256*27 + kk];
      acc2 += xvv * wb[2*256*27 + kk];
      acc3 += xvv * wb[3*256*27 + kk];
    }
    __syncthreads();
  }
  float sp = sp_f(scale[0]);
  float pa = prelu_a[0];
  int lsp = z*256 + ty*16 + tx;
  float accs[4] = {acc0,acc1,acc2,acc3};
  #pragma unroll
  for(int j=0;j<4;j++){
    int c = cg*4 + j;
    float cv = accs[j];
    cv = cv>0.f ? cv : pa*cv;
    out[((size_t)b*256 + c)*4096 + lsp] = hbuf[((size_t)b*4096 + lsp)*256 + c] + sp*cv;
  }
}

extern "C" void kernel_launch(void* const* d_in, const int* in_sizes, int n_in,
                              void* d_out, int out_size, void* d_ws, size_t ws_size,
                              hipStream_t stream) {
  const float* x         = (const float*)d_in[0];
  const float* ln_w      = (const float*)d_in[1];
  const float* ln_b      = (const float*)d_in[2];
  const float* in_proj_w = (const float*)d_in[3];
  const float* conv_w    = (const float*)d_in[4];
  const float* conv_b    = (const float*)d_in[5];
  const float* x_proj_w  = (const float*)d_in[6];
  const float* dt_proj_w = (const float*)d_in[7];
  const float* dt_proj_b = (const float*)d_in[8];
  const float* A_log     = (const float*)d_in[9];
  const float* D_skip    = (const float*)d_in[10];
  const float* out_proj_w= (const float*)d_in[11];
  const float* conv3d_w  = (const float*)d_in[12];
  const float* prelu_a   = (const float*)d_in[13];
  const float* scale     = (const float*)d_in[14];
  float* out = (float*)d_out;

  // workspace layout (floats); y aliases dt (scan reads dt[t] before writing y[t])
  float* ws   = (float*)d_ws;
  float* h    = ws;                    // 2,097,152  (B*L, 256)
  float* xz   = h    + 2097152;        // 8,388,608  (B*L, 1024)
  float* u    = xz   + 8388608;        // 4,194,304  (B*L, 512)
  float* xdbl = u    + 4194304;        //   393,216  (B*L, 48)
  float* dt   = xdbl + 393216;         // 4,194,304  (B*L, 512)
  float* y    = dt;                    // alias

  ln_kernel<<<LSEQ*2, 64, 0, stream>>>(x, ln_w, ln_b, h);

  for(int dep=0; dep<2; dep++){
    const float* in_w = in_proj_w + (size_t)dep*1024*256;
    const float* cw   = conv_w    + (size_t)dep*512*4;
    const float* cb   = conv_b    + (size_t)dep*512;
    const float* xpw  = x_proj_w  + (size_t)dep*48*512;
    const float* dtw  = dt_proj_w + (size_t)dep*512*16;
    const float* dtb  = dt_proj_b + (size_t)dep*512;
    const float* Alg  = A_log     + (size_t)dep*512*16;
    const float* Dsk  = D_skip    + (size_t)dep*512;
    const float* ow   = out_proj_w+ (size_t)dep*256*512;

    gemm_kernel<0><<<dim3(1024/64, 8192/64), dim3(16,16), 0, stream>>>(
        h, 256, in_w, nullptr, xz, 1024, 8192, 1024, 256);
    conv1d_silu_kernel<<<16384, 256, 0, stream>>>(xz, cw, cb, u);
    gemm_kernel<0><<<dim3(1, 8192/64), dim3(16,16), 0, stream>>>(
        u, 512, xpw, nullptr, xdbl, 48, 8192, 48, 512);
    gemm_kernel<1><<<dim3(512/64, 8192/64), dim3(16,16), 0, stream>>>(
        xdbl, 48, dtw, dtb, dt, 512, 8192, 512, 16);
    scan_kernel<<<64, 256, 0, stream>>>(dt, u, xdbl, Alg, y);
    ymul_kernel<<<16384, 256, 0, stream>>>(y, u, xz, Dsk);
    gemm_kernel<0><<<dim3(256/64, 8192/64), dim3(16,16), 0, stream>>>(
        y, 512, ow, nullptr, h, 256, 8192, 256, 512);
  }

  conv3d_out_kernel<<<dim3(64,16,2), 256, 0, stream>>>(
      x, conv3d_w, h, prelu_a, scale, out);
}

// Round 2
// 1690.370 us; speedup vs baseline: 2.9334x; 2.9334x over previous
//
#include <hip/hip_runtime.h>
#include <math.h>

#define LSEQ 4096
#define DIMC 256
#define DI   512
#define NCH  64     // chunks over L
#define CHL  64     // chunk length

__device__ __forceinline__ float sp_f(float v){ return fmaxf(v,0.f) + log1pf(__expf(-fabsf(v))); }
__device__ __forceinline__ float silu_f(float v){ return v/(1.f+__expf(-v)); }

// ---------------- LayerNorm over channel dim: x (B,C,L) -> h (B*L, C) ----------------
__global__ __launch_bounds__(64) void ln_kernel(const float* __restrict__ x,
                                                const float* __restrict__ w,
                                                const float* __restrict__ bias,
                                                float* __restrict__ h){
  int row = blockIdx.x;            // b*L + l
  int b = row >> 12, l = row & 4095;
  int i = threadIdx.x;             // 0..63
  const float* xb = x + (size_t)b*DIMC*LSEQ + l;
  float v[4]; float s=0.f, sq=0.f;
  #pragma unroll
  for(int j=0;j<4;j++){ float t = xb[(size_t)(j*64+i)*LSEQ]; v[j]=t; s+=t; sq+=t*t; }
  #pragma unroll
  for(int o=1;o<64;o<<=1){ s += __shfl_xor(s,o); sq += __shfl_xor(sq,o); }
  float mu = s*(1.f/256.f);
  float var = sq*(1.f/256.f) - mu*mu;
  float rs = rsqrtf(var + 1e-5f);
  float* hr = h + (size_t)row*DIMC;
  #pragma unroll
  for(int j=0;j<4;j++){ int c=j*64+i; hr[c] = (v[j]-mu)*rs*w[c] + bias[c]; }
}

// ---------------- Generic fp32 GEMM: C[M,N] = A[M,K] * W[N,K]^T (+ epilogue) --------
// EPI 0: none.  EPI 1: softplus(acc + bias[n])
template<int EPI>
__global__ __launch_bounds__(256) void gemm_kernel(const float* __restrict__ A, int lda,
                                                   const float* __restrict__ W,
                                                   const float* __restrict__ bias,
                                                   float* __restrict__ C, int ldc,
                                                   int M, int N, int K){
  __shared__ float As[16][64];
  __shared__ float Bs[16][64];
  int tx = threadIdx.x, ty = threadIdx.y;
  int tid = ty*16+tx;
  int n0 = blockIdx.x*64, m0 = blockIdx.y*64;
  float acc[4][4] = {};
  int lr = tid>>2;        // 0..63 (row within tile)
  int kq = (tid&3)*4;     // 0,4,8,12
  for(int k0=0;k0<K;k0+=16){
    float4 av = *(const float4*)(A + (size_t)(m0+lr)*lda + k0 + kq);
    As[kq+0][lr]=av.x; As[kq+1][lr]=av.y; As[kq+2][lr]=av.z; As[kq+3][lr]=av.w;
    float4 wv = make_float4(0.f,0.f,0.f,0.f);
    if(n0+lr < N) wv = *(const float4*)(W + (size_t)(n0+lr)*K + k0 + kq);
    Bs[kq+0][lr]=wv.x; Bs[kq+1][lr]=wv.y; Bs[kq+2][lr]=wv.z; Bs[kq+3][lr]=wv.w;
    __syncthreads();
    #pragma unroll
    for(int kk=0;kk<16;kk++){
      float4 a4 = *(const float4*)&As[kk][ty*4];
      float4 b4 = *(const float4*)&Bs[kk][tx*4];
      float aa[4]={a4.x,a4.y,a4.z,a4.w}, bb[4]={b4.x,b4.y,b4.z,b4.w};
      #pragma unroll
      for(int i2=0;i2<4;i2++)
        #pragma unroll
        for(int j2=0;j2<4;j2++) acc[i2][j2] += aa[i2]*bb[j2];
    }
    __syncthreads();
  }
  #pragma unroll
  for(int i2=0;i2<4;i2++){
    int m = m0 + ty*4 + i2;
    #pragma unroll
    for(int j2=0;j2<4;j2++){
      int n = n0 + tx*4 + j2;
      if(n < N){
        float vv = acc[i2][j2];
        if(EPI==1) vv = sp_f(vv + bias[n]);
        C[(size_t)m*ldc + n] = vv;
      }
    }
  }
}

// ---------------- causal depthwise conv1d (kernel 4) + bias + SiLU -------------------
__global__ __launch_bounds__(256) void conv1d_silu_kernel(const float* __restrict__ xz,
                                                          const float* __restrict__ cw,
                                                          const float* __restrict__ cb,
                                                          float* __restrict__ u){
  int g = blockIdx.x*256 + threadIdx.x;   // b*2^21 + l*512 + d
  int d = g & 511;
  int l = (g>>9) & 4095;
  int b = g >> 21;
  const float* ub = xz + (size_t)b*LSEQ*1024 + d;
  float accv = cb[d];
  #pragma unroll
  for(int k=0;k<4;k++){
    int ls = l-3+k;
    float vv = (ls>=0) ? ub[(size_t)ls*1024] : 0.f;
    accv += vv * cw[d*4+k];
  }
  u[(size_t)g] = silu_f(accv);
}

// ================= chunked selective scan ===========================================
// thread decomposition (G = global thread id):
//   s = G&15, dl = (G>>4)&3, c = (G>>6)&63, dh = (G>>12)&127, b = G>>19; d = dh*4+dl
// wave = 16 s-lanes x 4 consecutive d; chunk-major aggregate storage -> coalesced.

// pass1: per-chunk aggregates (prod dA, local h end with h0=0)
__global__ __launch_bounds__(256) void scan_pass1(const float* __restrict__ dt,
                                                  const float* __restrict__ u,
                                                  const float* __restrict__ xdbl,
                                                  const float* __restrict__ A_log,
                                                  float* __restrict__ Ap,
                                                  float* __restrict__ Ep){
  int G = blockIdx.x*256 + threadIdx.x;
  int s  = G & 15;
  int dl = (G>>4)&3;
  int c  = (G>>6)&63;
  int dh = (G>>12)&127;
  int b  = G>>19;
  int d  = dh*4 + dl;
  float a = -__expf(A_log[d*16+s]);
  const float* dtp = dt + (size_t)b*LSEQ*512 + d;
  const float* up  = u  + (size_t)b*LSEQ*512 + d;
  const float* xb  = xdbl + (size_t)b*LSEQ*48;
  int t0 = c*CHL;
  float aprod = 1.f, h = 0.f;
  for(int tt=0;tt<CHL;tt++){
    int t = t0+tt;
    float dtv = dtp[(size_t)t*512];
    float uv  = up[(size_t)t*512];
    float bv  = xb[t*48 + 16 + s];
    float dA  = __expf(dtv*a);
    h = dA*h + dtv*bv*uv;
    aprod *= dA;
  }
  int idx = b*8192 + d*16 + s;       // 0..16383
  Ap[(size_t)c*16384 + idx] = aprod;
  Ep[(size_t)c*16384 + idx] = h;
}

// pass2: exclusive scan over chunks, in place: Ep[c] <- h_start(chunk c)
__global__ __launch_bounds__(256) void scan_pass2(const float* __restrict__ Ap,
                                                  float* __restrict__ Ep){
  int idx = blockIdx.x*256 + threadIdx.x;   // 0..16383
  float h = 0.f;
  for(int c=0;c<NCH;c++){
    float a = Ap[(size_t)c*16384 + idx];
    float e = Ep[(size_t)c*16384 + idx];
    Ep[(size_t)c*16384 + idx] = h;
    h = a*h + e;
  }
}

// pass3: recompute h from h_start, reduce y over s, fused (y+u*D)*silu(z) epilogue
__global__ __launch_bounds__(256) void scan_pass3(const float* __restrict__ dt,
                                                  const float* __restrict__ u,
                                                  const float* __restrict__ xz,
                                                  const float* __restrict__ xdbl,
                                                  const float* __restrict__ A_log,
                                                  const float* __restrict__ Ep,
                                                  const float* __restrict__ Dsk,
                                                  float* __restrict__ y){
  int G = blockIdx.x*256 + threadIdx.x;
  int s  = G & 15;
  int dl = (G>>4)&3;
  int c  = (G>>6)&63;
  int dh = (G>>12)&127;
  int b  = G>>19;
  int d  = dh*4 + dl;
  float a = -__expf(A_log[d*16+s]);
  const float* dtp = dt + (size_t)b*LSEQ*512 + d;
  const float* up  = u  + (size_t)b*LSEQ*512 + d;
  const float* xb  = xdbl + (size_t)b*LSEQ*48;
  float* yp = y + (size_t)b*LSEQ*512 + d;
  int idx = b*8192 + d*16 + s;
  float h = Ep[(size_t)c*16384 + idx];
  float dskv = Dsk[d];
  int t0 = c*CHL;
  for(int tt=0;tt<CHL;tt++){
    int t = t0+tt;
    float dtv = dtp[(size_t)t*512];
    float uv  = up[(size_t)t*512];
    float bv  = xb[t*48 + 16 + s];
    float cv  = xb[t*48 + 32 + s];
    float dA  = __expf(dtv*a);
    h = dA*h + dtv*bv*uv;
    float pp = h*cv;
    pp += __shfl_xor(pp,1);
    pp += __shfl_xor(pp,2);
    pp += __shfl_xor(pp,4);
    pp += __shfl_xor(pp,8);
    if(s==0){
      float z = xz[(size_t)(b*LSEQ + t)*1024 + 512 + d];
      yp[(size_t)t*512] = (pp + uv*dskv) * silu_f(z);   // aliases dt[t]: read-before-write in-wave
    }
  }
}

// ---------------- conv3d 3x3x3 (pad 1) + PReLU + add mamba output --------------------
__global__ __launch_bounds__(256) void conv3d_out_kernel(const float* __restrict__ x,
                                                         const float* __restrict__ w3,
                                                         const float* __restrict__ hbuf,
                                                         const float* __restrict__ prelu_a,
                                                         const float* __restrict__ scale,
                                                         float* __restrict__ out){
  __shared__ float sm[3*18*18];
  int tx = threadIdx.x & 15, ty = threadIdx.x >> 4;
  int cg = blockIdx.x;        // 0..63 -> c = cg*4 + j
  int z  = blockIdx.y;        // 0..15
  int b  = blockIdx.z;        // 0..1
  float acc0=0.f, acc1=0.f, acc2=0.f, acc3=0.f;
  for(int ci=0; ci<256; ci++){
    const float* xs = x + (size_t)(b*256+ci)*4096;
    for(int idx=threadIdx.x; idx<972; idx+=256){
      int dz = idx/324, rem = idx - dz*324;
      int yy = rem/18, xx = rem - yy*18;
      int zz = z + dz - 1, ys = yy - 1, xsrc = xx - 1;
      float vv = 0.f;
      if((unsigned)zz < 16u && (unsigned)ys < 16u && (unsigned)xsrc < 16u)
        vv = xs[(zz*16 + ys)*16 + xsrc];
      sm[idx] = vv;
    }
    __syncthreads();
    float xv[27];
    #pragma unroll
    for(int kz=0;kz<3;kz++)
      #pragma unroll
      for(int ky=0;ky<3;ky++)
        #pragma unroll
        for(int kx=0;kx<3;kx++)
          xv[(kz*3+ky)*3+kx] = sm[kz*324 + (ty+ky)*18 + (tx+kx)];
    const float* wb = w3 + ((size_t)(cg*4)*256 + ci)*27;  // block-uniform -> scalar loads
    #pragma unroll
    for(int kk=0; kk<27; kk++){
      float xvv = xv[kk];
      acc0 += xvv * wb[kk];
      acc1 += xvv * wb[1*256*27 + kk];
      acc2 += xvv * wb[2*256*27 + kk];
      acc3 += xvv * wb[3*256*27 + kk];
    }
    __syncthreads();
  }
  float sp = sp_f(scale[0]);
  float pa = prelu_a[0];
  int lsp = z*256 + ty*16 + tx;
  float accs[4] = {acc0,acc1,acc2,acc3};
  #pragma unroll
  for(int j=0;j<4;j++){
    int c = cg*4 + j;
    float cv = accs[j];
    cv = cv>0.f ? cv : pa*cv;
    out[((size_t)b*256 + c)*4096 + lsp] = hbuf[((size_t)b*4096 + lsp)*256 + c] + sp*cv;
  }
}

extern "C" void kernel_launch(void* const* d_in, const int* in_sizes, int n_in,
                              void* d_out, int out_size, void* d_ws, size_t ws_size,
                              hipStream_t stream) {
  const float* x         = (const float*)d_in[0];
  const float* ln_w      = (const float*)d_in[1];
  const float* ln_b      = (const float*)d_in[2];
  const float* in_proj_w = (const float*)d_in[3];
  const float* conv_w    = (const float*)d_in[4];
  const float* conv_b    = (const float*)d_in[5];
  const float* x_proj_w  = (const float*)d_in[6];
  const float* dt_proj_w = (const float*)d_in[7];
  const float* dt_proj_b = (const float*)d_in[8];
  const float* A_log     = (const float*)d_in[9];
  const float* D_skip    = (const float*)d_in[10];
  const float* out_proj_w= (const float*)d_in[11];
  const float* conv3d_w  = (const float*)d_in[12];
  const float* prelu_a   = (const float*)d_in[13];
  const float* scale     = (const float*)d_in[14];
  float* out = (float*)d_out;

  // workspace layout (floats); y aliases dt; Ap/Ep alias h (dead between in/out proj)
  float* ws   = (float*)d_ws;
  float* h    = ws;                    // 2,097,152  (B*L, 256)
  float* xz   = h    + 2097152;        // 8,388,608  (B*L, 1024)
  float* u    = xz   + 8388608;        // 4,194,304  (B*L, 512)
  float* xdbl = u    + 4194304;        //   393,216  (B*L, 48)
  float* dt   = xdbl + 393216;         // 4,194,304  (B*L, 512)
  float* y    = dt;                    // alias
  float* Ap   = h;                     // 1,048,576  (NCH, 16384) — alias h
  float* Ep   = h + 1048576;           // 1,048,576  (NCH, 16384) — alias h

  ln_kernel<<<LSEQ*2, 64, 0, stream>>>(x, ln_w, ln_b, h);

  for(int dep=0; dep<2; dep++){
    const float* in_w = in_proj_w + (size_t)dep*1024*256;
    const float* cw   = conv_w    + (size_t)dep*512*4;
    const float* cb   = conv_b    + (size_t)dep*512;
    const float* xpw  = x_proj_w  + (size_t)dep*48*512;
    const float* dtw  = dt_proj_w + (size_t)dep*512*16;
    const float* dtb  = dt_proj_b + (size_t)dep*512;
    const float* Alg  = A_log     + (size_t)dep*512*16;
    const float* Dsk  = D_skip    + (size_t)dep*512;
    const float* ow   = out_proj_w+ (size_t)dep*256*512;

    gemm_kernel<0><<<dim3(1024/64, 8192/64), dim3(16,16), 0, stream>>>(
        h, 256, in_w, nullptr, xz, 1024, 8192, 1024, 256);
    conv1d_silu_kernel<<<16384, 256, 0, stream>>>(xz, cw, cb, u);
    gemm_kernel<0><<<dim3(1, 8192/64), dim3(16,16), 0, stream>>>(
        u, 512, xpw, nullptr, xdbl, 48, 8192, 48, 512);
    gemm_kernel<1><<<dim3(512/64, 8192/64), dim3(16,16), 0, stream>>>(
        xdbl, 48, dtw, dtb, dt, 512, 8192, 512, 16);

    scan_pass1<<<4096, 256, 0, stream>>>(dt, u, xdbl, Alg, Ap, Ep);
    scan_pass2<<<64, 256, 0, stream>>>(Ap, Ep);
    scan_pass3<<<4096, 256, 0, stream>>>(dt, u, xz, xdbl, Alg, Ep, Dsk, y);

    gemm_kernel<0><<<dim3(256/64, 8192/64), dim3(16,16), 0, stream>>>(
        y, 512, ow, nullptr, h, 256, 8192, 256, 512);
  }

  conv3d_out_kernel<<<dim3(64,16,2), 256, 0, stream>>>(
      x, conv3d_w, h, prelu_a, scale, out);
}

// Round 5
// 809.736 us; speedup vs baseline: 6.1236x; 2.0876x over previous
//
#include <hip/hip_runtime.h>
#include <math.h>

#define LSEQ 4096
#define DIMC 256
#define DI   512
#define NCH  64     // chunks over L
#define CHL  64     // chunk length

typedef short short8 __attribute__((ext_vector_type(8)));
typedef float f32x4 __attribute__((ext_vector_type(4)));

__device__ __forceinline__ float sp_f(float v){ return fmaxf(v,0.f) + log1pf(__expf(-fabsf(v))); }
__device__ __forceinline__ float silu_f(float v){ return v/(1.f+__expf(-v)); }
__device__ __forceinline__ unsigned short f2bf(float f){
  unsigned u = __builtin_bit_cast(unsigned, f);
  unsigned r = (u + 0x7FFFu + ((u>>16)&1u)) >> 16;
  return (unsigned short)r;
}

// ---------------- LayerNorm over channel dim: x (B,C,L) -> h (B*L, C) ----------------
__global__ __launch_bounds__(64) void ln_kernel(const float* __restrict__ x,
                                                const float* __restrict__ w,
                                                const float* __restrict__ bias,
                                                float* __restrict__ h){
  int row = blockIdx.x;            // b*L + l
  int b = row >> 12, l = row & 4095;
  int i = threadIdx.x;             // 0..63
  const float* xb = x + (size_t)b*DIMC*LSEQ + l;
  float v[4]; float s=0.f, sq=0.f;
  #pragma unroll
  for(int j=0;j<4;j++){ float t = xb[(size_t)(j*64+i)*LSEQ]; v[j]=t; s+=t; sq+=t*t; }
  #pragma unroll
  for(int o=1;o<64;o<<=1){ s += __shfl_xor(s,o); sq += __shfl_xor(sq,o); }
  float mu = s*(1.f/256.f);
  float var = sq*(1.f/256.f) - mu*mu;
  float rs = rsqrtf(var + 1e-5f);
  float* hr = h + (size_t)row*DIMC;
  #pragma unroll
  for(int j=0;j<4;j++){ int c=j*64+i; hr[c] = (v[j]-mu)*rs*w[c] + bias[c]; }
}

// ---------------- Generic fp32 GEMM: C[M,N] = A[M,K] * W[N,K]^T (+ epilogue) --------
template<int EPI>
__global__ __launch_bounds__(256) void gemm_kernel(const float* __restrict__ A, int lda,
                                                   const float* __restrict__ W,
                                                   const float* __restrict__ bias,
                                                   float* __restrict__ C, int ldc,
                                                   int M, int N, int K){
  __shared__ float As[16][64];
  __shared__ float Bs[16][64];
  int tx = threadIdx.x, ty = threadIdx.y;
  int tid = ty*16+tx;
  int n0 = blockIdx.x*64, m0 = blockIdx.y*64;
  float acc[4][4] = {};
  int lr = tid>>2;        // 0..63 (row within tile)
  int kq = (tid&3)*4;     // 0,4,8,12
  for(int k0=0;k0<K;k0+=16){
    float4 av = *(const float4*)(A + (size_t)(m0+lr)*lda + k0 + kq);
    As[kq+0][lr]=av.x; As[kq+1][lr]=av.y; As[kq+2][lr]=av.z; As[kq+3][lr]=av.w;
    float4 wv = make_float4(0.f,0.f,0.f,0.f);
    if(n0+lr < N) wv = *(const float4*)(W + (size_t)(n0+lr)*K + k0 + kq);
    Bs[kq+0][lr]=wv.x; Bs[kq+1][lr]=wv.y; Bs[kq+2][lr]=wv.z; Bs[kq+3][lr]=wv.w;
    __syncthreads();
    #pragma unroll
    for(int kk=0;kk<16;kk++){
      float4 a4 = *(const float4*)&As[kk][ty*4];
      float4 b4 = *(const float4*)&Bs[kk][tx*4];
      float aa[4]={a4.x,a4.y,a4.z,a4.w}, bb[4]={b4.x,b4.y,b4.z,b4.w};
      #pragma unroll
      for(int i2=0;i2<4;i2++)
        #pragma unroll
        for(int j2=0;j2<4;j2++) acc[i2][j2] += aa[i2]*bb[j2];
    }
    __syncthreads();
  }
  #pragma unroll
  for(int i2=0;i2<4;i2++){
    int m = m0 + ty*4 + i2;
    #pragma unroll
    for(int j2=0;j2<4;j2++){
      int n = n0 + tx*4 + j2;
      if(n < N){
        float vv = acc[i2][j2];
        if(EPI==1) vv = sp_f(vv + bias[n]);
        C[(size_t)m*ldc + n] = vv;
      }
    }
  }
}

// ---------------- causal depthwise conv1d (kernel 4) + bias + SiLU -------------------
__global__ __launch_bounds__(256) void conv1d_silu_kernel(const float* __restrict__ xz,
                                                          const float* __restrict__ cw,
                                                          const float* __restrict__ cb,
                                                          float* __restrict__ u){
  int g = blockIdx.x*256 + threadIdx.x;   // b*2^21 + l*512 + d
  int d = g & 511;
  int l = (g>>9) & 4095;
  int b = g >> 21;
  const float* ub = xz + (size_t)b*LSEQ*1024 + d;
  float accv = cb[d];
  #pragma unroll
  for(int k=0;k<4;k++){
    int ls = l-3+k;
    float vv = (ls>=0) ? ub[(size_t)ls*1024] : 0.f;
    accv += vv * cw[d*4+k];
  }
  u[(size_t)g] = silu_f(accv);
}

// ================= chunked selective scan ===========================================
__global__ __launch_bounds__(256) void scan_pass1(const float* __restrict__ dt,
                                                  const float* __restrict__ u,
                                                  const float* __restrict__ xdbl,
                                                  const float* __restrict__ A_log,
                                                  float* __restrict__ Ap,
                                                  float* __restrict__ Ep){
  int G = blockIdx.x*256 + threadIdx.x;
  int s  = G & 15;
  int dl = (G>>4)&3;
  int c  = (G>>6)&63;
  int dh = (G>>12)&127;
  int b  = G>>19;
  int d  = dh*4 + dl;
  float a = -__expf(A_log[d*16+s]);
  const float* dtp = dt + (size_t)b*LSEQ*512 + d;
  const float* up  = u  + (size_t)b*LSEQ*512 + d;
  const float* xb  = xdbl + (size_t)b*LSEQ*48;
  int t0 = c*CHL;
  float aprod = 1.f, h = 0.f;
  for(int tt=0;tt<CHL;tt++){
    int t = t0+tt;
    float dtv = dtp[(size_t)t*512];
    float uv  = up[(size_t)t*512];
    float bv  = xb[t*48 + 16 + s];
    float dA  = __expf(dtv*a);
    h = dA*h + dtv*bv*uv;
    aprod *= dA;
  }
  int idx = b*8192 + d*16 + s;       // 0..16383
  Ap[(size_t)c*16384 + idx] = aprod;
  Ep[(size_t)c*16384 + idx] = h;
}

__global__ __launch_bounds__(256) void scan_pass2(const float* __restrict__ Ap,
                                                  float* __restrict__ Ep){
  int idx = blockIdx.x*256 + threadIdx.x;   // 0..16383
  float h = 0.f;
  for(int c=0;c<NCH;c++){
    float a = Ap[(size_t)c*16384 + idx];
    float e = Ep[(size_t)c*16384 + idx];
    Ep[(size_t)c*16384 + idx] = h;
    h = a*h + e;
  }
}

__global__ __launch_bounds__(256) void scan_pass3(const float* __restrict__ dt,
                                                  const float* __restrict__ u,
                                                  const float* __restrict__ xz,
                                                  const float* __restrict__ xdbl,
                                                  const float* __restrict__ A_log,
                                                  const float* __restrict__ Ep,
                                                  const float* __restrict__ Dsk,
                                                  float* __restrict__ y){
  int G = blockIdx.x*256 + threadIdx.x;
  int s  = G & 15;
  int dl = (G>>4)&3;
  int c  = (G>>6)&63;
  int dh = (G>>12)&127;
  int b  = G>>19;
  int d  = dh*4 + dl;
  float a = -__expf(A_log[d*16+s]);
  const float* dtp = dt + (size_t)b*LSEQ*512 + d;
  const float* up  = u  + (size_t)b*LSEQ*512 + d;
  const float* xb  = xdbl + (size_t)b*LSEQ*48;
  float* yp = y + (size_t)b*LSEQ*512 + d;
  int idx = b*8192 + d*16 + s;
  float h = Ep[(size_t)c*16384 + idx];
  float dskv = Dsk[d];
  int t0 = c*CHL;
  for(int tt=0;tt<CHL;tt++){
    int t = t0+tt;
    float dtv = dtp[(size_t)t*512];
    float uv  = up[(size_t)t*512];
    float bv  = xb[t*48 + 16 + s];
    float cv  = xb[t*48 + 32 + s];
    float dA  = __expf(dtv*a);
    h = dA*h + dtv*bv*uv;
    float pp = h*cv;
    pp += __shfl_xor(pp,1);
    pp += __shfl_xor(pp,2);
    pp += __shfl_xor(pp,4);
    pp += __shfl_xor(pp,8);
    if(s==0){
      float z = xz[(size_t)(b*LSEQ + t)*1024 + 512 + d];
      yp[(size_t)t*512] = (pp + uv*dskv) * silu_f(z);   // aliases dt[t]: read-before-write in-wave
    }
  }
}

// ================= conv3d via bf16 MFMA implicit GEMM ===============================
// single-writer padded fill: every byte of xt written exactly once per call.
// grid 648 = b(2) x zz(18) x yy(18); block writes one (b,zz,yy) row: 18 x-pos x 256 ci
__global__ __launch_bounds__(256) void xt_fill(const float* __restrict__ x,
                                               unsigned short* __restrict__ xt){
  int bid = blockIdx.x;
  int b = bid / 324; int r = bid - b*324;
  int zz = r / 18, yy = r - zz*18;
  bool inner = (zz>=1 && zz<=16 && yy>=1 && yy<=16);
  unsigned short* xd = xt + (size_t)((b*18 + zz)*18 + yy)*18*256;
  const float* xs = x + (size_t)b*256*4096 + (zz-1)*256 + (yy-1)*16;
  int t = threadIdx.x;
  for(int u = t; u < 576; u += 256){
    int xpos = u >> 5;           // 0..17
    int ci0 = (u & 31) * 8;
    uint4 val = make_uint4(0,0,0,0);
    if(inner && xpos>=1 && xpos<=16){
      int xi = xpos-1;
      unsigned pk[4];
      #pragma unroll
      for(int j=0;j<4;j++){
        unsigned short lo = f2bf(xs[(size_t)(ci0+2*j  )*4096 + xi]);
        unsigned short hi = f2bf(xs[(size_t)(ci0+2*j+1)*4096 + xi]);
        pk[j] = (unsigned)lo | ((unsigned)hi << 16);
      }
      val = make_uint4(pk[0],pk[1],pk[2],pk[3]);
    }
    *(uint4*)(xd + (size_t)u*8) = val;
  }
}

// wt[co*6912 + tap*256 + ci] = bf16(w3[co*6912 + ci*27 + tap])
__global__ __launch_bounds__(256) void wt_conv(const float* __restrict__ w3,
                                               unsigned short* __restrict__ wt){
  int idx = blockIdx.x*256 + threadIdx.x;   // 0..1,769,471
  int ci = idx & 255; int r = idx >> 8;     // 0..6911
  int tap = r % 27, co = r / 27;
  wt[idx] = f2bf(w3[(size_t)co*6912 + ci*27 + tap]);
}

// main: D[co][m] = sum_k W[co][k] * Xcol[k][m], k = tap*256+ci; fused prelu+add epilogue
// grid 256: 64 m-tiles(128) x 4 co-tiles(64); 4 waves = 2(m) x 2(co); wave = 32co x 64m
__global__ __launch_bounds__(256) void conv3d_mfma(const unsigned short* __restrict__ xt,
                                                   const unsigned short* __restrict__ wt,
                                                   const float* __restrict__ hbuf,
                                                   const float* __restrict__ prelu_a,
                                                   const float* __restrict__ scale,
                                                   float* __restrict__ out){
  int bid = blockIdx.x;
  int ntile = bid & 3;          // co-tile of 64
  int mtile = bid >> 2;         // m-tile of 128
  int tid = threadIdx.x;
  int l  = tid & 63;
  int w  = tid >> 6;
  int w_co = w & 1, w_m = w >> 1;
  int lr = l & 15;              // row/col within fragment
  int lk = l >> 4;              // k-subgroup (x8)

  const unsigned short* aptr = wt + (size_t)(ntile*64 + w_co*32 + lr)*6912 + lk*8;
  int m0 = mtile*128 + w_m*64 + lr;
  int b = m0 >> 12, sp0 = m0 & 4095;
  int z = sp0 >> 8, y = (sp0 >> 4) & 15, x = sp0 & 15;
  const unsigned short* bptr = xt + (size_t)(((b*18 + z+1)*18 + (y+1))*18 + (x+1))*256 + lk*8;

  f32x4 acc[2][4] = {};
  for(int tap=0; tap<27; ++tap){
    int dz = tap/9 - 1; int rem = tap - (tap/9)*9;
    int dy = rem/3 - 1, dx = rem - (rem/3)*3 - 1;
    const unsigned short* ap = aptr + tap*256;
    const unsigned short* bp = bptr + (dz*324 + dy*18 + dx)*256;
    #pragma unroll
    for(int c8=0; c8<8; ++c8){
      short8 a0 = *(const short8*)(ap);
      short8 a1 = *(const short8*)(ap + 16*6912);
      short8 b0 = *(const short8*)(bp);
      short8 b1 = *(const short8*)(bp + 4608);
      short8 b2 = *(const short8*)(bp + 2*4608);
      short8 b3 = *(const short8*)(bp + 3*4608);
      acc[0][0] = __builtin_amdgcn_mfma_f32_16x16x32_bf16(a0, b0, acc[0][0], 0,0,0);
      acc[0][1] = __builtin_amdgcn_mfma_f32_16x16x32_bf16(a0, b1, acc[0][1], 0,0,0);
      acc[0][2] = __builtin_amdgcn_mfma_f32_16x16x32_bf16(a0, b2, acc[0][2], 0,0,0);
      acc[0][3] = __builtin_amdgcn_mfma_f32_16x16x32_bf16(a0, b3, acc[0][3], 0,0,0);
      acc[1][0] = __builtin_amdgcn_mfma_f32_16x16x32_bf16(a1, b0, acc[1][0], 0,0,0);
      acc[1][1] = __builtin_amdgcn_mfma_f32_16x16x32_bf16(a1, b1, acc[1][1], 0,0,0);
      acc[1][2] = __builtin_amdgcn_mfma_f32_16x16x32_bf16(a1, b2, acc[1][2], 0,0,0);
      acc[1][3] = __builtin_amdgcn_mfma_f32_16x16x32_bf16(a1, b3, acc[1][3], 0,0,0);
      ap += 32; bp += 32;
    }
  }
  float spv = sp_f(scale[0]);
  float pa = prelu_a[0];
  #pragma unroll
  for(int fc=0; fc<2; ++fc){
    #pragma unroll
    for(int fm=0; fm<4; ++fm){
      int m = mtile*128 + w_m*64 + fm*16 + lr;
      int bb = m >> 12, sp = m & 4095;
      #pragma unroll
      for(int r=0; r<4; ++r){
        int co = ntile*64 + w_co*32 + fc*16 + 4*lk + r;
        float cval = acc[fc][fm][r];
        float pr = cval > 0.f ? cval : pa*cval;
        out[((size_t)(bb*256 + co))*4096 + sp] = hbuf[(size_t)m*256 + co] + spv*pr;
      }
    }
  }
}

extern "C" void kernel_launch(void* const* d_in, const int* in_sizes, int n_in,
                              void* d_out, int out_size, void* d_ws, size_t ws_size,
                              hipStream_t stream) {
  const float* x         = (const float*)d_in[0];
  const float* ln_w      = (const float*)d_in[1];
  const float* ln_b      = (const float*)d_in[2];
  const float* in_proj_w = (const float*)d_in[3];
  const float* conv_w    = (const float*)d_in[4];
  const float* conv_b    = (const float*)d_in[5];
  const float* x_proj_w  = (const float*)d_in[6];
  const float* dt_proj_w = (const float*)d_in[7];
  const float* dt_proj_b = (const float*)d_in[8];
  const float* A_log     = (const float*)d_in[9];
  const float* D_skip    = (const float*)d_in[10];
  const float* out_proj_w= (const float*)d_in[11];
  const float* conv3d_w  = (const float*)d_in[12];
  const float* prelu_a   = (const float*)d_in[13];
  const float* scale     = (const float*)d_in[14];
  float* out = (float*)d_out;

  float* ws   = (float*)d_ws;
  float* h    = ws;                    // 2,097,152  (B*L, 256)
  float* xz   = h    + 2097152;        // 8,388,608  (B*L, 1024)
  float* u    = xz   + 8388608;        // 4,194,304  (B*L, 512)
  float* xdbl = u    + 4194304;        //   393,216  (B*L, 48)
  float* dt   = xdbl + 393216;         // 4,194,304  (B*L, 512)
  float* y    = dt;                    // alias (R2-proven)
  float* Ap   = h;                     // alias h (R2-proven; dead between projections)
  float* Ep   = h + 1048576;

  // conv3d prep buffers: dedicated tail region when ws permits (no alias),
  // else fall back to aliasing the dead xz region.
  const size_t base_floats = 19267584;              // 77,070,336 bytes
  const size_t conv_bytes  = (2985984u + 1769472u) * 2u;  // 9,510,912
  unsigned short* xt;
  if (ws_size >= base_floats*4 + conv_bytes) {
    xt = (unsigned short*)(ws + base_floats);
  } else {
    xt = (unsigned short*)xz;
  }
  unsigned short* wt = xt + 2985984;

  ln_kernel<<<LSEQ*2, 64, 0, stream>>>(x, ln_w, ln_b, h);

  for(int dep=0; dep<2; dep++){
    const float* in_w = in_proj_w + (size_t)dep*1024*256;
    const float* cw   = conv_w    + (size_t)dep*512*4;
    const float* cb   = conv_b    + (size_t)dep*512;
    const float* xpw  = x_proj_w  + (size_t)dep*48*512;
    const float* dtw  = dt_proj_w + (size_t)dep*512*16;
    const float* dtb  = dt_proj_b + (size_t)dep*512;
    const float* Alg  = A_log     + (size_t)dep*512*16;
    const float* Dsk  = D_skip    + (size_t)dep*512;
    const float* ow   = out_proj_w+ (size_t)dep*256*512;

    gemm_kernel<0><<<dim3(1024/64, 8192/64), dim3(16,16), 0, stream>>>(
        h, 256, in_w, nullptr, xz, 1024, 8192, 1024, 256);
    conv1d_silu_kernel<<<16384, 256, 0, stream>>>(xz, cw, cb, u);
    gemm_kernel<0><<<dim3(1, 8192/64), dim3(16,16), 0, stream>>>(
        u, 512, xpw, nullptr, xdbl, 48, 8192, 48, 512);
    gemm_kernel<1><<<dim3(512/64, 8192/64), dim3(16,16), 0, stream>>>(
        xdbl, 48, dtw, dtb, dt, 512, 8192, 512, 16);

    scan_pass1<<<4096, 256, 0, stream>>>(dt, u, xdbl, Alg, Ap, Ep);
    scan_pass2<<<64, 256, 0, stream>>>(Ap, Ep);
    scan_pass3<<<4096, 256, 0, stream>>>(dt, u, xz, xdbl, Alg, Ep, Dsk, y);

    gemm_kernel<0><<<dim3(256/64, 8192/64), dim3(16,16), 0, stream>>>(
        y, 512, ow, nullptr, h, 256, 8192, 256, 512);
  }

  // conv3d prep + MFMA conv with fused epilogue
  xt_fill<<<648, 256, 0, stream>>>(x, xt);
  wt_conv<<<6912, 256, 0, stream>>>(conv3d_w, wt);
  conv3d_mfma<<<256, 256, 0, stream>>>(xt, wt, h, prelu_a, scale, out);
}

// Round 7
// 712.610 us; speedup vs baseline: 6.9582x; 1.1363x over previous
//
#include <hip/hip_runtime.h>
#include <math.h>

#define LSEQ 4096
#define DIMC 256
#define DI   512
#define NCH  64     // chunks over L
#define CHL  64     // chunk length

typedef short short8 __attribute__((ext_vector_type(8)));
typedef float f32x4 __attribute__((ext_vector_type(4)));

__device__ __forceinline__ float sp_f(float v){ return fmaxf(v,0.f) + log1pf(__expf(-fabsf(v))); }
__device__ __forceinline__ float silu_f(float v){ return v/(1.f+__expf(-v)); }
__device__ __forceinline__ unsigned short f2bf(float f){
  unsigned u = __builtin_bit_cast(unsigned, f);
  unsigned r = (u + 0x7FFFu + ((u>>16)&1u)) >> 16;
  return (unsigned short)r;
}
__device__ __forceinline__ float bf2f(unsigned short us){
  unsigned u = ((unsigned)us)<<16;
  return __builtin_bit_cast(float, u);
}

// ---------------- LayerNorm: x (B,C,L) -> h_bf (B*L, C) bf16 -------------------------
__global__ __launch_bounds__(64) void ln_kernel(const float* __restrict__ x,
                                                const float* __restrict__ w,
                                                const float* __restrict__ bias,
                                                unsigned short* __restrict__ hb){
  int row = blockIdx.x;            // b*L + l
  int b = row >> 12, l = row & 4095;
  int i = threadIdx.x;             // 0..63
  const float* xb = x + (size_t)b*DIMC*LSEQ + l;
  float v[4]; float s=0.f, sq=0.f;
  #pragma unroll
  for(int j=0;j<4;j++){ float t = xb[(size_t)(j*64+i)*LSEQ]; v[j]=t; s+=t; sq+=t*t; }
  #pragma unroll
  for(int o=1;o<64;o<<=1){ s += __shfl_xor(s,o); sq += __shfl_xor(sq,o); }
  float mu = s*(1.f/256.f);
  float var = sq*(1.f/256.f) - mu*mu;
  float rs = rsqrtf(var + 1e-5f);
  unsigned short* hr = hb + (size_t)row*DIMC;
  #pragma unroll
  for(int j=0;j<4;j++){ int c=j*64+i; hr[c] = f2bf((v[j]-mu)*rs*w[c] + bias[c]); }
}

// ---------------- generic bf16 copy of weights ---------------------------------------
__global__ __launch_bounds__(256) void cvt_bf(const float* __restrict__ src,
                                              unsigned short* __restrict__ dst, int n){
  int i = blockIdx.x*256 + threadIdx.x;
  if(i < n) dst[i] = f2bf(src[i]);
}

// ---------------- W_dt[dep][n][k] = sum_j dtw[dep][n][j] * xpw[dep][j][k] ------------
__global__ __launch_bounds__(256) void wdt_kernel(const float* __restrict__ dtw,
                                                  const float* __restrict__ xpw,
                                                  unsigned short* __restrict__ wdt){
  int idx = blockIdx.x*256 + threadIdx.x;   // 0..524287
  int dep = idx >> 18;
  int r = idx & 262143;
  int n = r >> 9, k = r & 511;
  const float* dw = dtw + (size_t)dep*512*16 + n*16;
  const float* xp = xpw + (size_t)dep*48*512 + k;
  float acc = 0.f;
  #pragma unroll
  for(int j=0;j<16;j++) acc += dw[j] * xp[(size_t)j*512];
  wdt[idx] = f2bf(acc);
}

// ---------------- all-global bf16 MFMA GEMM: D[n][m] = W[n,:]·A[m,:] -----------------
// A: M×K bf16; W: N×K bf16. Wave tile (FN*16 n)×(FM*16 m), block WM×WN waves.
// EPI1: softplus(v+bias[n]). WF: fp32 out. WB: bf16 out. (single-output instantiations only)
template<int FM,int FN,int WM,int WN,int EPI,int WF,int WB>
__global__ __launch_bounds__(WM*WN*64) void gemm_mfma(
    const unsigned short* __restrict__ A,
    const unsigned short* __restrict__ W,
    const float* __restrict__ bias,
    float* __restrict__ Cf,
    unsigned short* __restrict__ Cb,
    int M, int N, int K){
  int tid = threadIdx.x;
  int l = tid & 63, w = tid >> 6;
  int w_n = w % WN, w_m = w / WN;
  int lr = l & 15, lk = l >> 4;
  int nb = blockIdx.x * (WN*FN*16) + w_n*(FN*16);
  int mb = blockIdx.y * (WM*FM*16) + w_m*(FM*16);
  const unsigned short* ap[FN];
  const unsigned short* bp[FM];
  #pragma unroll
  for(int i=0;i<FN;i++) ap[i] = W + (size_t)(nb + i*16 + lr)*K + lk*8;
  #pragma unroll
  for(int i=0;i<FM;i++) bp[i] = A + (size_t)(mb + i*16 + lr)*K + lk*8;
  f32x4 acc[FN][FM] = {};
  for(int k0=0;k0<K;k0+=32){
    short8 av[FN], bv[FM];
    #pragma unroll
    for(int i=0;i<FN;i++) av[i] = *(const short8*)(ap[i]);
    #pragma unroll
    for(int i=0;i<FM;i++) bv[i] = *(const short8*)(bp[i]);
    #pragma unroll
    for(int i=0;i<FN;i++)
      #pragma unroll
      for(int j=0;j<FM;j++)
        acc[i][j] = __builtin_amdgcn_mfma_f32_16x16x32_bf16(av[i], bv[j], acc[i][j], 0,0,0);
    #pragma unroll
    for(int i=0;i<FN;i++) ap[i] += 32;
    #pragma unroll
    for(int i=0;i<FM;i++) bp[i] += 32;
  }
  #pragma unroll
  for(int i=0;i<FN;i++){
    #pragma unroll
    for(int j=0;j<FM;j++){
      int m = mb + j*16 + lr;
      #pragma unroll
      for(int r=0;r<4;r++){
        int n = nb + i*16 + 4*lk + r;
        float v = acc[i][j][r];
        if(EPI==1) v = sp_f(v + bias[n]);
        if(WF) Cf[(size_t)m*N + n] = v;
        if(WB) Cb[(size_t)m*N + n] = f2bf(v);
      }
    }
  }
}

// ---------------- causal depthwise conv1d (k=4) + bias + SiLU -> u_bf ---------------
__global__ __launch_bounds__(256) void conv1d_silu_kernel(const float* __restrict__ xz,
                                                          const float* __restrict__ cw,
                                                          const float* __restrict__ cb,
                                                          unsigned short* __restrict__ ub){
  int g = blockIdx.x*256 + threadIdx.x;   // b*2^21 + l*512 + d
  int d = g & 511;
  int l = (g>>9) & 4095;
  int b = g >> 21;
  const float* up = xz + (size_t)b*LSEQ*1024 + d;
  float accv = cb[d];
  #pragma unroll
  for(int k=0;k<4;k++){
    int ls = l-3+k;
    float vv = (ls>=0) ? up[(size_t)ls*1024] : 0.f;
    accv += vv * cw[d*4+k];
  }
  ub[(size_t)g] = f2bf(silu_f(accv));
}

// ================= chunked selective scan (dt,u bf16; xdbl fp32 [B|C] 32/row) =======
__global__ __launch_bounds__(256) void scan_pass1(const unsigned short* __restrict__ dt,
                                                  const unsigned short* __restrict__ u,
                                                  const float* __restrict__ xdbl,
                                                  const float* __restrict__ A_log,
                                                  float* __restrict__ Ap,
                                                  float* __restrict__ Ep){
  int G = blockIdx.x*256 + threadIdx.x;
  int s  = G & 15;
  int dl = (G>>4)&3;
  int c  = (G>>6)&63;
  int dh = (G>>12)&127;
  int b  = G>>19;
  int d  = dh*4 + dl;
  float a = -__expf(A_log[d*16+s]);
  const unsigned short* dtp = dt + (size_t)b*LSEQ*512 + d;
  const unsigned short* up  = u  + (size_t)b*LSEQ*512 + d;
  const float* xb  = xdbl + (size_t)b*LSEQ*32;
  int t0 = c*CHL;
  float aprod = 1.f, h = 0.f;
  for(int tt=0;tt<CHL;tt++){
    int t = t0+tt;
    float dtv = bf2f(dtp[(size_t)t*512]);
    float uv  = bf2f(up[(size_t)t*512]);
    float bv  = xb[t*32 + s];
    float dA  = __expf(dtv*a);
    h = dA*h + dtv*bv*uv;
    aprod *= dA;
  }
  int idx = b*8192 + d*16 + s;       // 0..16383
  Ap[(size_t)c*16384 + idx] = aprod;
  Ep[(size_t)c*16384 + idx] = h;
}

__global__ __launch_bounds__(256) void scan_pass2(const float* __restrict__ Ap,
                                                  float* __restrict__ Ep){
  int idx = blockIdx.x*256 + threadIdx.x;   // 0..16383
  float h = 0.f;
  for(int c=0;c<NCH;c++){
    float a = Ap[(size_t)c*16384 + idx];
    float e = Ep[(size_t)c*16384 + idx];
    Ep[(size_t)c*16384 + idx] = h;
    h = a*h + e;
  }
}

__global__ __launch_bounds__(256) void scan_pass3(const unsigned short* __restrict__ dt,
                                                  const unsigned short* __restrict__ u,
                                                  const float* __restrict__ xz,
                                                  const float* __restrict__ xdbl,
                                                  const float* __restrict__ A_log,
                                                  const float* __restrict__ Ep,
                                                  const float* __restrict__ Dsk,
                                                  unsigned short* __restrict__ yb){
  int G = blockIdx.x*256 + threadIdx.x;
  int s  = G & 15;
  int dl = (G>>4)&3;
  int c  = (G>>6)&63;
  int dh = (G>>12)&127;
  int b  = G>>19;
  int d  = dh*4 + dl;
  float a = -__expf(A_log[d*16+s]);
  const unsigned short* dtp = dt + (size_t)b*LSEQ*512 + d;
  const unsigned short* up  = u  + (size_t)b*LSEQ*512 + d;
  const float* xb  = xdbl + (size_t)b*LSEQ*32;
  unsigned short* yp = yb + (size_t)b*LSEQ*512 + d;
  int idx = b*8192 + d*16 + s;
  float h = Ep[(size_t)c*16384 + idx];
  float dskv = Dsk[d];
  int t0 = c*CHL;
  for(int tt=0;tt<CHL;tt++){
    int t = t0+tt;
    float dtv = bf2f(dtp[(size_t)t*512]);
    float uv  = bf2f(up[(size_t)t*512]);
    float bv  = xb[t*32 + s];
    float cv  = xb[t*32 + 16 + s];
    float dA  = __expf(dtv*a);
    h = dA*h + dtv*bv*uv;
    float pp = h*cv;
    pp += __shfl_xor(pp,1);
    pp += __shfl_xor(pp,2);
    pp += __shfl_xor(pp,4);
    pp += __shfl_xor(pp,8);
    if(s==0){
      float z = xz[(size_t)(b*LSEQ + t)*1024 + 512 + d];
      yp[(size_t)t*512] = f2bf((pp + uv*dskv) * silu_f(z));
    }
  }
}

// ================= conv3d via bf16 MFMA implicit GEMM ===============================
// single-writer padded fill: every byte of xt written exactly once per call.
__global__ __launch_bounds__(256) void xt_fill(const float* __restrict__ x,
                                               unsigned short* __restrict__ xt){
  int bid = blockIdx.x;
  int b = bid / 324; int r = bid - b*324;
  int zz = r / 18, yy = r - zz*18;
  bool inner = (zz>=1 && zz<=16 && yy>=1 && yy<=16);
  unsigned short* xd = xt + (size_t)((b*18 + zz)*18 + yy)*18*256;
  const float* xs = x + (size_t)b*256*4096 + (zz-1)*256 + (yy-1)*16;
  int t = threadIdx.x;
  for(int u = t; u < 576; u += 256){
    int xpos = u >> 5;           // 0..17
    int ci0 = (u & 31) * 8;
    uint4 val = make_uint4(0,0,0,0);
    if(inner && xpos>=1 && xpos<=16){
      int xi = xpos-1;
      unsigned pk[4];
      #pragma unroll
      for(int j=0;j<4;j++){
        unsigned short lo = f2bf(xs[(size_t)(ci0+2*j  )*4096 + xi]);
        unsigned short hi = f2bf(xs[(size_t)(ci0+2*j+1)*4096 + xi]);
        pk[j] = (unsigned)lo | ((unsigned)hi << 16);
      }
      val = make_uint4(pk[0],pk[1],pk[2],pk[3]);
    }
    *(uint4*)(xd + (size_t)u*8) = val;
  }
}

__global__ __launch_bounds__(256) void wt_conv(const float* __restrict__ w3,
                                               unsigned short* __restrict__ wt){
  int idx = blockIdx.x*256 + threadIdx.x;   // 0..1,769,471
  int ci = idx & 255; int r = idx >> 8;     // 0..6911
  int tap = r % 27, co = r / 27;
  wt[idx] = f2bf(w3[(size_t)co*6912 + ci*27 + tap]);
}

// 512 blocks: 128 m-tiles(64) x 4 co-tiles(64); 4 waves = 2(co) x 2(m); wave 32co x 32m
// skip-add reads h_bf (bf16)
__global__ __launch_bounds__(256) void conv3d_mfma(const unsigned short* __restrict__ xt,
                                                   const unsigned short* __restrict__ wt,
                                                   const unsigned short* __restrict__ hb,
                                                   const float* __restrict__ prelu_a,
                                                   const float* __restrict__ scale,
                                                   float* __restrict__ out){
  int bid = blockIdx.x;
  int ntile = bid & 3;          // co-tile of 64
  int mtile = bid >> 2;         // m-tile of 64 (0..127)
  int tid = threadIdx.x;
  int l  = tid & 63;
  int w  = tid >> 6;
  int w_co = w & 1, w_m = w >> 1;
  int lr = l & 15;              // row/col within fragment
  int lk = l >> 4;              // k-subgroup (x8)

  const unsigned short* aptr = wt + (size_t)(ntile*64 + w_co*32 + lr)*6912 + lk*8;
  int m0 = mtile*64 + w_m*32 + lr;
  int b = m0 >> 12, sp0 = m0 & 4095;
  int z = sp0 >> 8, y = (sp0 >> 4) & 15, x = sp0 & 15;
  const unsigned short* bptr = xt + (size_t)(((b*18 + z+1)*18 + (y+1))*18 + (x+1))*256 + lk*8;

  f32x4 acc[2][2] = {};
  for(int tap=0; tap<27; ++tap){
    int dz = tap/9 - 1; int rem = tap - (tap/9)*9;
    int dy = rem/3 - 1, dx = rem - (rem/3)*3 - 1;
    const unsigned short* ap = aptr + tap*256;
    const unsigned short* bp = bptr + (dz*324 + dy*18 + dx)*256;
    #pragma unroll
    for(int c8=0; c8<8; ++c8){
      short8 a0 = *(const short8*)(ap);
      short8 a1 = *(const short8*)(ap + 16*6912);
      short8 b0 = *(const short8*)(bp);
      short8 b1 = *(const short8*)(bp + 4608);     // +16 m = +1 y-row (no y-carry by tiling)
      acc[0][0] = __builtin_amdgcn_mfma_f32_16x16x32_bf16(a0, b0, acc[0][0], 0,0,0);
      acc[0][1] = __builtin_amdgcn_mfma_f32_16x16x32_bf16(a0, b1, acc[0][1], 0,0,0);
      acc[1][0] = __builtin_amdgcn_mfma_f32_16x16x32_bf16(a1, b0, acc[1][0], 0,0,0);
      acc[1][1] = __builtin_amdgcn_mfma_f32_16x16x32_bf16(a1, b1, acc[1][1], 0,0,0);
      ap += 32; bp += 32;
    }
  }
  float spv = sp_f(scale[0]);
  float pa = prelu_a[0];
  #pragma unroll
  for(int fc=0; fc<2; ++fc){
    #pragma unroll
    for(int fm=0; fm<2; ++fm){
      int m = mtile*64 + w_m*32 + fm*16 + lr;
      int bb = m >> 12, sp = m & 4095;
      #pragma unroll
      for(int r=0; r<4; ++r){
        int co = ntile*64 + w_co*32 + fc*16 + 4*lk + r;
        float cval = acc[fc][fm][r];
        float pr = cval > 0.f ? cval : pa*cval;
        out[((size_t)(bb*256 + co))*4096 + sp] = bf2f(hb[(size_t)m*256 + co]) + spv*pr;
      }
    }
  }
}

extern "C" void kernel_launch(void* const* d_in, const int* in_sizes, int n_in,
                              void* d_out, int out_size, void* d_ws, size_t ws_size,
                              hipStream_t stream) {
  const float* x         = (const float*)d_in[0];
  const float* ln_w      = (const float*)d_in[1];
  const float* ln_b      = (const float*)d_in[2];
  const float* in_proj_w = (const float*)d_in[3];
  const float* conv_w    = (const float*)d_in[4];
  const float* conv_b    = (const float*)d_in[5];
  const float* x_proj_w  = (const float*)d_in[6];
  const float* dt_proj_w = (const float*)d_in[7];
  const float* dt_proj_b = (const float*)d_in[8];
  const float* A_log     = (const float*)d_in[9];
  const float* D_skip    = (const float*)d_in[10];
  const float* out_proj_w= (const float*)d_in[11];
  const float* conv3d_w  = (const float*)d_in[12];
  const float* prelu_a   = (const float*)d_in[13];
  const float* scale     = (const float*)d_in[14];
  float* out = (float*)d_out;

  // workspace layout (float offsets) — NO aliasing anywhere; one producer per phase.
  float* ws   = (float*)d_ws;
  float* Ap   = ws;                               // 1,048,576 fl (scan scratch, dedicated)
  float* Ep   = Ap + 1048576;                     // 1,048,576 fl
  float* xz   = Ep + 1048576;                     // 8,388,608 fl (B*L,1024) fp32
  unsigned short* u_bf  = (unsigned short*)(xz + 8388608);     // 4,194,304 bf16
  float* xdbl = (float*)(u_bf + 4194304);         // 262,144 fl (B*L,32) [B|C]
  unsigned short* dt_bf = (unsigned short*)(xdbl + 262144);    // 4,194,304 bf16
  unsigned short* h_bf  = dt_bf + 4194304;        // 2,097,152 bf16
  unsigned short* y_bf  = h_bf + 2097152;         // 4,194,304 bf16
  unsigned short* inw_bf   = y_bf + 4194304;      // 524,288 bf16
  unsigned short* ow_bf    = inw_bf + 524288;     // 262,144 bf16
  unsigned short* xpwbc_bf = ow_bf + 262144;      // 32,768 bf16
  unsigned short* wdt_bf   = xpwbc_bf + 32768;    // 524,288 bf16
  // base ends at 18,759,680 floats = 75,038,720 bytes
  const size_t base_floats = 18759680;
  const size_t conv_bytes  = (2985984u + 1769472u) * 2u;   // 9,510,912
  unsigned short* xt;
  if (ws_size >= base_floats*4 + conv_bytes) {
    xt = (unsigned short*)(ws + base_floats);     // dedicated tail
  } else {
    xt = (unsigned short*)xz;                     // xz dead at conv3d time
  }
  unsigned short* wt = xt + 2985984;

  // ---- weight prep (bf16) ----
  cvt_bf<<<2048, 256, 0, stream>>>(in_proj_w, inw_bf, 524288);
  cvt_bf<<<1024, 256, 0, stream>>>(out_proj_w, ow_bf, 262144);
  cvt_bf<<<64, 256, 0, stream>>>(x_proj_w + 16*512, xpwbc_bf, 16384);
  cvt_bf<<<64, 256, 0, stream>>>(x_proj_w + 48*512 + 16*512, xpwbc_bf + 16384, 16384);
  wdt_kernel<<<2048, 256, 0, stream>>>(dt_proj_w, x_proj_w, wdt_bf);

  ln_kernel<<<LSEQ*2, 64, 0, stream>>>(x, ln_w, ln_b, h_bf);

  for(int dep=0; dep<2; dep++){
    const unsigned short* inw = inw_bf   + (size_t)dep*262144;
    const unsigned short* oww = ow_bf    + (size_t)dep*131072;
    const unsigned short* xpw = xpwbc_bf + (size_t)dep*16384;
    const unsigned short* wdt = wdt_bf   + (size_t)dep*262144;
    const float* cw   = conv_w    + (size_t)dep*512*4;
    const float* cb   = conv_b    + (size_t)dep*512;
    const float* dtb  = dt_proj_b + (size_t)dep*512;
    const float* Alg  = A_log     + (size_t)dep*512*16;
    const float* Dsk  = D_skip    + (size_t)dep*512;

    // in_proj: xz[8192,1024] = h_bf @ inw^T
    gemm_mfma<4,2,2,2,0,1,0><<<dim3(16,64), 256, 0, stream>>>(
        h_bf, inw, nullptr, xz, nullptr, 8192, 1024, 256);
    conv1d_silu_kernel<<<16384, 256, 0, stream>>>(xz, cw, cb, u_bf);
    // x_proj B,C: xdbl[8192,32] = u_bf @ xpw_bc^T
    gemm_mfma<2,2,4,1,0,1,0><<<dim3(1,64), 256, 0, stream>>>(
        u_bf, xpw, nullptr, xdbl, nullptr, 8192, 32, 512);
    // dt (folded): dt_bf[8192,512] = softplus(u_bf @ wdt^T + dtb)
    gemm_mfma<4,2,2,2,1,0,1><<<dim3(8,64), 256, 0, stream>>>(
        u_bf, wdt, dtb, nullptr, dt_bf, 8192, 512, 512);

    scan_pass1<<<4096, 256, 0, stream>>>(dt_bf, u_bf, xdbl, Alg, Ap, Ep);
    scan_pass2<<<64, 256, 0, stream>>>(Ap, Ep);
    scan_pass3<<<4096, 256, 0, stream>>>(dt_bf, u_bf, xz, xdbl, Alg, Ep, Dsk, y_bf);

    // out_proj: h_bf[8192,256] = y_bf @ ow^T   (single bf16 output)
    gemm_mfma<2,2,2,2,0,0,1><<<dim3(4,128), 256, 0, stream>>>(
        y_bf, oww, nullptr, nullptr, h_bf, 8192, 256, 512);
  }

  // conv3d prep + MFMA conv with fused epilogue (skip-add from h_bf)
  xt_fill<<<648, 256, 0, stream>>>(x, xt);
  wt_conv<<<6912, 256, 0, stream>>>(conv3d_w, wt);
  conv3d_mfma<<<512, 256, 0, stream>>>(xt, wt, h_bf, prelu_a, scale, out);
}

// Round 8
// 660.412 us; speedup vs baseline: 7.5082x; 1.0790x over previous
//
#include <hip/hip_runtime.h>
#include <math.h>

#define LSEQ 4096
#define DIMC 256
#define DI   512
#define NCH  64     // chunks over L
#define CHL  64     // chunk length

typedef short short8 __attribute__((ext_vector_type(8)));
typedef float f32x4 __attribute__((ext_vector_type(4)));

__device__ __forceinline__ float sp_f(float v){ return fmaxf(v,0.f) + log1pf(__expf(-fabsf(v))); }
__device__ __forceinline__ float silu_f(float v){ return v/(1.f+__expf(-v)); }
__device__ __forceinline__ unsigned short f2bf(float f){
  unsigned u = __builtin_bit_cast(unsigned, f);
  unsigned r = (u + 0x7FFFu + ((u>>16)&1u)) >> 16;
  return (unsigned short)r;
}
__device__ __forceinline__ float bf2f(unsigned short us){
  unsigned u = ((unsigned)us)<<16;
  return __builtin_bit_cast(float, u);
}

// ---------------- LayerNorm: x (B,C,L) -> h_bf (B*L, C) bf16 -------------------------
__global__ __launch_bounds__(64) void ln_kernel(const float* __restrict__ x,
                                                const float* __restrict__ w,
                                                const float* __restrict__ bias,
                                                unsigned short* __restrict__ hb){
  int row = blockIdx.x;            // b*L + l
  int b = row >> 12, l = row & 4095;
  int i = threadIdx.x;             // 0..63
  const float* xb = x + (size_t)b*DIMC*LSEQ + l;
  float v[4]; float s=0.f, sq=0.f;
  #pragma unroll
  for(int j=0;j<4;j++){ float t = xb[(size_t)(j*64+i)*LSEQ]; v[j]=t; s+=t; sq+=t*t; }
  #pragma unroll
  for(int o=1;o<64;o<<=1){ s += __shfl_xor(s,o); sq += __shfl_xor(sq,o); }
  float mu = s*(1.f/256.f);
  float var = sq*(1.f/256.f) - mu*mu;
  float rs = rsqrtf(var + 1e-5f);
  unsigned short* hr = hb + (size_t)row*DIMC;
  #pragma unroll
  for(int j=0;j<4;j++){ int c=j*64+i; hr[c] = f2bf((v[j]-mu)*rs*w[c] + bias[c]); }
}

// ---------------- generic bf16 copy of weights ---------------------------------------
__global__ __launch_bounds__(256) void cvt_bf(const float* __restrict__ src,
                                              unsigned short* __restrict__ dst, int n){
  int i = blockIdx.x*256 + threadIdx.x;
  if(i < n) dst[i] = f2bf(src[i]);
}

// ---------------- W_dt[dep][n][k] = sum_j dtw[dep][n][j] * xpw[dep][j][k] ------------
__global__ __launch_bounds__(256) void wdt_kernel(const float* __restrict__ dtw,
                                                  const float* __restrict__ xpw,
                                                  unsigned short* __restrict__ wdt){
  int idx = blockIdx.x*256 + threadIdx.x;   // 0..524287
  int dep = idx >> 18;
  int r = idx & 262143;
  int n = r >> 9, k = r & 511;
  const float* dw = dtw + (size_t)dep*512*16 + n*16;
  const float* xp = xpw + (size_t)dep*48*512 + k;
  float acc = 0.f;
  #pragma unroll
  for(int j=0;j<16;j++) acc += dw[j] * xp[(size_t)j*512];
  wdt[idx] = f2bf(acc);
}

// ---------------- all-global bf16 MFMA GEMM: D[n][m] = W[n,:]·A[m,:] -----------------
// A: M×K bf16; W: N×K bf16. Wave tile (FN*16 n)×(FM*16 m), block WM×WN waves.
// EPI1: softplus(v+bias[n]). WF: fp32 out. WB: bf16 out.
template<int FM,int FN,int WM,int WN,int EPI,int WF,int WB>
__global__ __launch_bounds__(WM*WN*64) void gemm_mfma(
    const unsigned short* __restrict__ A,
    const unsigned short* __restrict__ W,
    const float* __restrict__ bias,
    float* __restrict__ Cf,
    unsigned short* __restrict__ Cb,
    int M, int N, int K){
  int tid = threadIdx.x;
  int l = tid & 63, w = tid >> 6;
  int w_n = w % WN, w_m = w / WN;
  int lr = l & 15, lk = l >> 4;
  int nb = blockIdx.x * (WN*FN*16) + w_n*(FN*16);
  int mb = blockIdx.y * (WM*FM*16) + w_m*(FM*16);
  const unsigned short* ap[FN];
  const unsigned short* bp[FM];
  #pragma unroll
  for(int i=0;i<FN;i++) ap[i] = W + (size_t)(nb + i*16 + lr)*K + lk*8;
  #pragma unroll
  for(int i=0;i<FM;i++) bp[i] = A + (size_t)(mb + i*16 + lr)*K + lk*8;
  f32x4 acc[FN][FM] = {};
  for(int k0=0;k0<K;k0+=32){
    short8 av[FN], bv[FM];
    #pragma unroll
    for(int i=0;i<FN;i++) av[i] = *(const short8*)(ap[i]);
    #pragma unroll
    for(int i=0;i<FM;i++) bv[i] = *(const short8*)(bp[i]);
    #pragma unroll
    for(int i=0;i<FN;i++)
      #pragma unroll
      for(int j=0;j<FM;j++)
        acc[i][j] = __builtin_amdgcn_mfma_f32_16x16x32_bf16(av[i], bv[j], acc[i][j], 0,0,0);
    #pragma unroll
    for(int i=0;i<FN;i++) ap[i] += 32;
    #pragma unroll
    for(int i=0;i<FM;i++) bp[i] += 32;
  }
  #pragma unroll
  for(int i=0;i<FN;i++){
    #pragma unroll
    for(int j=0;j<FM;j++){
      int m = mb + j*16 + lr;
      #pragma unroll
      for(int r=0;r<4;r++){
        int n = nb + i*16 + 4*lk + r;
        float v = acc[i][j][r];
        if(EPI==1) v = sp_f(v + bias[n]);
        if(WF) Cf[(size_t)m*N + n] = v;
        if(WB) Cb[(size_t)m*N + n] = f2bf(v);
      }
    }
  }
}

// ---------------- causal depthwise conv1d (k=4) + bias + SiLU -> u_bf ---------------
__global__ __launch_bounds__(256) void conv1d_silu_kernel(const float* __restrict__ xz,
                                                          const float* __restrict__ cw,
                                                          const float* __restrict__ cb,
                                                          unsigned short* __restrict__ ub){
  int g = blockIdx.x*256 + threadIdx.x;   // b*2^21 + l*512 + d
  int d = g & 511;
  int l = (g>>9) & 4095;
  int b = g >> 21;
  const float* up = xz + (size_t)b*LSEQ*1024 + d;
  float accv = cb[d];
  #pragma unroll
  for(int k=0;k<4;k++){
    int ls = l-3+k;
    float vv = (ls>=0) ? up[(size_t)ls*1024] : 0.f;
    accv += vv * cw[d*4+k];
  }
  ub[(size_t)g] = f2bf(silu_f(accv));
}

// ================= chunked selective scan (dt,u bf16; xdbl fp32 [B|C] 32/row) =======
__global__ __launch_bounds__(256) void scan_pass1(const unsigned short* __restrict__ dt,
                                                  const unsigned short* __restrict__ u,
                                                  const float* __restrict__ xdbl,
                                                  const float* __restrict__ A_log,
                                                  float* __restrict__ Ap,
                                                  float* __restrict__ Ep){
  int G = blockIdx.x*256 + threadIdx.x;
  int s  = G & 15;
  int dl = (G>>4)&3;
  int c  = (G>>6)&63;
  int dh = (G>>12)&127;
  int b  = G>>19;
  int d  = dh*4 + dl;
  float a = -__expf(A_log[d*16+s]);
  const unsigned short* dtp = dt + (size_t)b*LSEQ*512 + d;
  const unsigned short* up  = u  + (size_t)b*LSEQ*512 + d;
  const float* xb  = xdbl + (size_t)b*LSEQ*32;
  int t0 = c*CHL;
  float aprod = 1.f, h = 0.f;
  for(int tt=0;tt<CHL;tt++){
    int t = t0+tt;
    float dtv = bf2f(dtp[(size_t)t*512]);
    float uv  = bf2f(up[(size_t)t*512]);
    float bv  = xb[t*32 + s];
    float dA  = __expf(dtv*a);
    h = dA*h + dtv*bv*uv;
    aprod *= dA;
  }
  int idx = b*8192 + d*16 + s;       // 0..16383
  Ap[(size_t)c*16384 + idx] = aprod;
  Ep[(size_t)c*16384 + idx] = h;
}

__global__ __launch_bounds__(256) void scan_pass2(const float* __restrict__ Ap,
                                                  float* __restrict__ Ep){
  int idx = blockIdx.x*256 + threadIdx.x;   // 0..16383
  float h = 0.f;
  for(int c=0;c<NCH;c++){
    float a = Ap[(size_t)c*16384 + idx];
    float e = Ep[(size_t)c*16384 + idx];
    Ep[(size_t)c*16384 + idx] = h;
    h = a*h + e;
  }
}

__global__ __launch_bounds__(256) void scan_pass3(const unsigned short* __restrict__ dt,
                                                  const unsigned short* __restrict__ u,
                                                  const float* __restrict__ xz,
                                                  const float* __restrict__ xdbl,
                                                  const float* __restrict__ A_log,
                                                  const float* __restrict__ Ep,
                                                  const float* __restrict__ Dsk,
                                                  unsigned short* __restrict__ yb){
  int G = blockIdx.x*256 + threadIdx.x;
  int s  = G & 15;
  int dl = (G>>4)&3;
  int c  = (G>>6)&63;
  int dh = (G>>12)&127;
  int b  = G>>19;
  int d  = dh*4 + dl;
  float a = -__expf(A_log[d*16+s]);
  const unsigned short* dtp = dt + (size_t)b*LSEQ*512 + d;
  const unsigned short* up  = u  + (size_t)b*LSEQ*512 + d;
  const float* xb  = xdbl + (size_t)b*LSEQ*32;
  unsigned short* yp = yb + (size_t)b*LSEQ*512 + d;
  int idx = b*8192 + d*16 + s;
  float h = Ep[(size_t)c*16384 + idx];
  float dskv = Dsk[d];
  int t0 = c*CHL;
  for(int tt=0;tt<CHL;tt++){
    int t = t0+tt;
    float dtv = bf2f(dtp[(size_t)t*512]);
    float uv  = bf2f(up[(size_t)t*512]);
    float bv  = xb[t*32 + s];
    float cv  = xb[t*32 + 16 + s];
    float dA  = __expf(dtv*a);
    h = dA*h + dtv*bv*uv;
    float pp = h*cv;
    pp += __shfl_xor(pp,1);
    pp += __shfl_xor(pp,2);
    pp += __shfl_xor(pp,4);
    pp += __shfl_xor(pp,8);
    if(s==0){
      float z = xz[(size_t)(b*LSEQ + t)*1024 + 512 + d];
      yp[(size_t)t*512] = f2bf((pp + uv*dskv) * silu_f(z));
    }
  }
}

// ================= conv3d via bf16 MFMA implicit GEMM ===============================
// single-writer padded fill: every byte of xt written exactly once per call.
__global__ __launch_bounds__(256) void xt_fill(const float* __restrict__ x,
                                               unsigned short* __restrict__ xt){
  int bid = blockIdx.x;
  int b = bid / 324; int r = bid - b*324;
  int zz = r / 18, yy = r - zz*18;
  bool inner = (zz>=1 && zz<=16 && yy>=1 && yy<=16);
  unsigned short* xd = xt + (size_t)((b*18 + zz)*18 + yy)*18*256;
  const float* xs = x + (size_t)b*256*4096 + (zz-1)*256 + (yy-1)*16;
  int t = threadIdx.x;
  for(int u = t; u < 576; u += 256){
    int xpos = u >> 5;           // 0..17
    int ci0 = (u & 31) * 8;
    uint4 val = make_uint4(0,0,0,0);
    if(inner && xpos>=1 && xpos<=16){
      int xi = xpos-1;
      unsigned pk[4];
      #pragma unroll
      for(int j=0;j<4;j++){
        unsigned short lo = f2bf(xs[(size_t)(ci0+2*j  )*4096 + xi]);
        unsigned short hi = f2bf(xs[(size_t)(ci0+2*j+1)*4096 + xi]);
        pk[j] = (unsigned)lo | ((unsigned)hi << 16);
      }
      val = make_uint4(pk[0],pk[1],pk[2],pk[3]);
    }
    *(uint4*)(xd + (size_t)u*8) = val;
  }
}

__global__ __launch_bounds__(256) void wt_conv(const float* __restrict__ w3,
                                               unsigned short* __restrict__ wt){
  int idx = blockIdx.x*256 + threadIdx.x;   // 0..1,769,471
  int ci = idx & 255; int r = idx >> 8;     // 0..6911
  int tap = r % 27, co = r / 27;
  wt[idx] = f2bf(w3[(size_t)co*6912 + ci*27 + tap]);
}

// 256 blocks: one 32-m tile x ALL 256 co per block; 4 waves = co quadrants.
// All 4 waves issue IDENTICAL B (xt) loads -> L1-shared, 8x less L3 traffic.
// Wave tile 64co x 32m: per c8-step 4 A + 2 B loads, 8 MFMAs.
__global__ __launch_bounds__(256) void conv3d_mfma(const unsigned short* __restrict__ xt,
                                                   const unsigned short* __restrict__ wt,
                                                   const unsigned short* __restrict__ hb,
                                                   const float* __restrict__ prelu_a,
                                                   const float* __restrict__ scale,
                                                   float* __restrict__ out){
  int mtile = blockIdx.x;       // 0..255 (32 m each)
  int tid = threadIdx.x;
  int l  = tid & 63;
  int w  = tid >> 6;            // co quadrant (64 co)
  int lr = l & 15;              // fragment row
  int lk = l >> 4;              // k-subgroup (x8)

  const unsigned short* aptr = wt + (size_t)(w*64 + lr)*6912 + lk*8;
  int m0 = mtile*32 + lr;
  int b = m0 >> 12, sp0 = m0 & 4095;
  int z = sp0 >> 8, y = (sp0 >> 4) & 15, x = sp0 & 15;
  const unsigned short* bptr = xt + (size_t)(((b*18 + z+1)*18 + (y+1))*18 + (x+1))*256 + lk*8;

  f32x4 acc[4][2] = {};
  for(int tap=0; tap<27; ++tap){
    int dz = tap/9 - 1; int rem = tap - (tap/9)*9;
    int dy = rem/3 - 1, dx = rem - (rem/3)*3 - 1;
    const unsigned short* ap = aptr + tap*256;
    const unsigned short* bp = bptr + (dz*324 + dy*18 + dx)*256;
    #pragma unroll
    for(int c8=0; c8<8; ++c8){
      short8 b0 = *(const short8*)(bp);
      short8 b1 = *(const short8*)(bp + 4608);     // +16 m = +1 y-row
      short8 a0 = *(const short8*)(ap);
      short8 a1 = *(const short8*)(ap + 16*6912);
      short8 a2 = *(const short8*)(ap + 32*6912);
      short8 a3 = *(const short8*)(ap + 48*6912);
      acc[0][0] = __builtin_amdgcn_mfma_f32_16x16x32_bf16(a0, b0, acc[0][0], 0,0,0);
      acc[0][1] = __builtin_amdgcn_mfma_f32_16x16x32_bf16(a0, b1, acc[0][1], 0,0,0);
      acc[1][0] = __builtin_amdgcn_mfma_f32_16x16x32_bf16(a1, b0, acc[1][0], 0,0,0);
      acc[1][1] = __builtin_amdgcn_mfma_f32_16x16x32_bf16(a1, b1, acc[1][1], 0,0,0);
      acc[2][0] = __builtin_amdgcn_mfma_f32_16x16x32_bf16(a2, b0, acc[2][0], 0,0,0);
      acc[2][1] = __builtin_amdgcn_mfma_f32_16x16x32_bf16(a2, b1, acc[2][1], 0,0,0);
      acc[3][0] = __builtin_amdgcn_mfma_f32_16x16x32_bf16(a3, b0, acc[3][0], 0,0,0);
      acc[3][1] = __builtin_amdgcn_mfma_f32_16x16x32_bf16(a3, b1, acc[3][1], 0,0,0);
      ap += 32; bp += 32;
    }
  }
  float spv = sp_f(scale[0]);
  float pa = prelu_a[0];
  #pragma unroll
  for(int fc=0; fc<4; ++fc){
    #pragma unroll
    for(int fm=0; fm<2; ++fm){
      int m = mtile*32 + fm*16 + lr;
      int bb = m >> 12, sp = m & 4095;
      #pragma unroll
      for(int r=0; r<4; ++r){
        int co = w*64 + fc*16 + 4*lk + r;
        float cval = acc[fc][fm][r];
        float pr = cval > 0.f ? cval : pa*cval;
        out[((size_t)(bb*256 + co))*4096 + sp] = bf2f(hb[(size_t)m*256 + co]) + spv*pr;
      }
    }
  }
}

extern "C" void kernel_launch(void* const* d_in, const int* in_sizes, int n_in,
                              void* d_out, int out_size, void* d_ws, size_t ws_size,
                              hipStream_t stream) {
  const float* x         = (const float*)d_in[0];
  const float* ln_w      = (const float*)d_in[1];
  const float* ln_b      = (const float*)d_in[2];
  const float* in_proj_w = (const float*)d_in[3];
  const float* conv_w    = (const float*)d_in[4];
  const float* conv_b    = (const float*)d_in[5];
  const float* x_proj_w  = (const float*)d_in[6];
  const float* dt_proj_w = (const float*)d_in[7];
  const float* dt_proj_b = (const float*)d_in[8];
  const float* A_log     = (const float*)d_in[9];
  const float* D_skip    = (const float*)d_in[10];
  const float* out_proj_w= (const float*)d_in[11];
  const float* conv3d_w  = (const float*)d_in[12];
  const float* prelu_a   = (const float*)d_in[13];
  const float* scale     = (const float*)d_in[14];
  float* out = (float*)d_out;

  // workspace layout (float offsets) — NO aliasing; one producer per phase.
  float* ws   = (float*)d_ws;
  float* Ap   = ws;                               // 1,048,576 fl
  float* Ep   = Ap + 1048576;                     // 1,048,576 fl
  float* xz   = Ep + 1048576;                     // 8,388,608 fl (B*L,1024) fp32
  unsigned short* u_bf  = (unsigned short*)(xz + 8388608);     // 4,194,304 bf16
  float* xdbl = (float*)(u_bf + 4194304);         // 262,144 fl (B*L,32) [B|C]
  unsigned short* dt_bf = (unsigned short*)(xdbl + 262144);    // 4,194,304 bf16
  unsigned short* h_bf  = dt_bf + 4194304;        // 2,097,152 bf16
  unsigned short* y_bf  = h_bf + 2097152;         // 4,194,304 bf16
  unsigned short* inw_bf   = y_bf + 4194304;      // 524,288 bf16
  unsigned short* ow_bf    = inw_bf + 524288;     // 262,144 bf16
  unsigned short* xpwbc_bf = ow_bf + 262144;      // 32,768 bf16
  unsigned short* wdt_bf   = xpwbc_bf + 32768;    // 524,288 bf16
  const size_t base_floats = 18759680;            // 75,038,720 bytes
  const size_t conv_bytes  = (2985984u + 1769472u) * 2u;   // 9,510,912
  unsigned short* xt;
  if (ws_size >= base_floats*4 + conv_bytes) {
    xt = (unsigned short*)(ws + base_floats);     // dedicated tail
  } else {
    xt = (unsigned short*)xz;                     // xz dead at conv3d time
  }
  unsigned short* wt = xt + 2985984;

  // ---- weight prep (bf16) ----
  cvt_bf<<<2048, 256, 0, stream>>>(in_proj_w, inw_bf, 524288);
  cvt_bf<<<1024, 256, 0, stream>>>(out_proj_w, ow_bf, 262144);
  cvt_bf<<<64, 256, 0, stream>>>(x_proj_w + 16*512, xpwbc_bf, 16384);
  cvt_bf<<<64, 256, 0, stream>>>(x_proj_w + 48*512 + 16*512, xpwbc_bf + 16384, 16384);
  wdt_kernel<<<2048, 256, 0, stream>>>(dt_proj_w, x_proj_w, wdt_bf);

  ln_kernel<<<LSEQ*2, 64, 0, stream>>>(x, ln_w, ln_b, h_bf);

  for(int dep=0; dep<2; dep++){
    const unsigned short* inw = inw_bf   + (size_t)dep*262144;
    const unsigned short* oww = ow_bf    + (size_t)dep*131072;
    const unsigned short* xpw = xpwbc_bf + (size_t)dep*16384;
    const unsigned short* wdt = wdt_bf   + (size_t)dep*262144;
    const float* cw   = conv_w    + (size_t)dep*512*4;
    const float* cb   = conv_b    + (size_t)dep*512;
    const float* dtb  = dt_proj_b + (size_t)dep*512;
    const float* Alg  = A_log     + (size_t)dep*512*16;
    const float* Dsk  = D_skip    + (size_t)dep*512;

    // in_proj: xz[8192,1024] = h_bf @ inw^T   (wave 64n x 64m, 512 blocks, 2 w/SIMD)
    gemm_mfma<4,4,2,2,0,1,0><<<dim3(8,64), 256, 0, stream>>>(
        h_bf, inw, nullptr, xz, nullptr, 8192, 1024, 256);
    conv1d_silu_kernel<<<16384, 256, 0, stream>>>(xz, cw, cb, u_bf);
    // x_proj B,C: xdbl[8192,32] = u_bf @ xpw_bc^T
    gemm_mfma<2,2,4,1,0,1,0><<<dim3(1,64), 256, 0, stream>>>(
        u_bf, xpw, nullptr, xdbl, nullptr, 8192, 32, 512);
    // dt (folded): dt_bf[8192,512] = softplus(u_bf @ wdt^T + dtb)  (256 blocks)
    gemm_mfma<4,4,2,2,1,0,1><<<dim3(4,64), 256, 0, stream>>>(
        u_bf, wdt, dtb, nullptr, dt_bf, 8192, 512, 512);

    scan_pass1<<<4096, 256, 0, stream>>>(dt_bf, u_bf, xdbl, Alg, Ap, Ep);
    scan_pass2<<<64, 256, 0, stream>>>(Ap, Ep);
    scan_pass3<<<4096, 256, 0, stream>>>(dt_bf, u_bf, xz, xdbl, Alg, Ep, Dsk, y_bf);

    // out_proj: h_bf[8192,256] = y_bf @ ow^T  (wave 64n x 32m, 256 blocks)
    gemm_mfma<2,4,2,2,0,0,1><<<dim3(2,128), 256, 0, stream>>>(
        y_bf, oww, nullptr, nullptr, h_bf, 8192, 256, 512);
  }

  // conv3d prep + MFMA conv with fused epilogue (skip-add from h_bf)
  xt_fill<<<648, 256, 0, stream>>>(x, xt);
  wt_conv<<<6912, 256, 0, stream>>>(conv3d_w, wt);
  conv3d_mfma<<<256, 256, 0, stream>>>(xt, wt, h_bf, prelu_a, scale, out);
}